// Round 2
// baseline (305.256 us; speedup 1.0000x reference)
//
#include <hip/hip_runtime.h>

#define NB 32
#define NP 512
#define NS 1024
#define NH 1024
#define NR 256
#define K3 3072

#define BM 32
#define BK 64
#define KP 72   // padded LDS pitch in shorts; 144 B stride -> 36 banks ≡ 4 (mod 32), uniform spread

typedef short short8 __attribute__((ext_vector_type(8)));
typedef __bf16 bf16x8 __attribute__((ext_vector_type(8)));
typedef float f32x4 __attribute__((ext_vector_type(4)));

__device__ __forceinline__ unsigned short f2bf(float f) {
  unsigned u = __builtin_bit_cast(unsigned, f);
  u += 0x7fffu + ((u >> 16) & 1u);   // round-to-nearest-even
  return (unsigned short)(u >> 16);
}

__device__ __forceinline__ f32x4 mfma_bf16(short8 a, short8 b, f32x4 c) {
  return __builtin_amdgcn_mfma_f32_16x16x32_bf16(
      __builtin_bit_cast(bf16x8, a), __builtin_bit_cast(bf16x8, b), c, 0, 0, 0);
}

// Convert W fp32 [R, 3H] -> bf16 copy in workspace (same layout).
__global__ void wconv_kernel(const float* __restrict__ W,
                             unsigned short* __restrict__ Wb) {
  int i = blockIdx.x * blockDim.x + threadIdx.x;   // one float4 per thread
  float4 v = ((const float4*)W)[i];
  ushort4 o;
  o.x = f2bf(v.x); o.y = f2bf(v.y); o.z = f2bf(v.z); o.w = f2bf(v.w);
  ((ushort4*)Wb)[i] = o;
}

// Fused gather + 3-part bf16 MFMA GEMM.
// Grid: 512 blocks (M-tiles of 32 pairs) -> 2 blocks/CU, 8 waves/CU.
// 256 threads = 4 waves; wave w owns output cols [w*64, w*64+64), tile 32x64.
// Per K-chunk (BK=64 of H): stage head/tail/prod 32x64 bf16 tiles in LDS
// (double-buffered, register-prefetched); W-frags read straight from L1/L2.
__global__ __launch_bounds__(256, 2) void gemm_kernel(
    const int* __restrict__ pairs, const float* __restrict__ hs,
    const unsigned short* __restrict__ Wb, const float* __restrict__ bias,
    float* __restrict__ out) {
  __shared__ __align__(16) unsigned short sA[2][3][BM][KP];  // 27648 B
  __shared__ int sPair[BM][4];

  const int tid   = threadIdx.x;
  const int blk   = blockIdx.x;
  const int batch = blk >> 4;          // 16 M-tiles per batch (512/32)
  const int m0    = blk * BM;          // global pair-row base

  if (tid < BM) {
    int4 pr = ((const int4*)pairs)[m0 + tid];
    sPair[tid][0] = pr.x; sPair[tid][1] = pr.y;
    sPair[tid][2] = pr.z; sPair[tid][3] = pr.w;
  }
  __syncthreads();

  // --- A staging: 8 threads per pair-row, 8 cols each (2 float4 per src row) ---
  const int arow = tid >> 3;
  const int q    = tid & 7;
  const float* hb  = hs + (size_t)batch * NS * NH;
  const float* pr0 = hb + (size_t)sPair[arow][0] * NH + q * 8;
  const float* pr1 = hb + (size_t)sPair[arow][1] * NH + q * 8;
  const float* pr2 = hb + (size_t)sPair[arow][2] * NH + q * 8;
  const float* pr3 = hb + (size_t)sPair[arow][3] * NH + q * 8;

  // --- MFMA lane mapping ---
  const int lane = tid & 63;
  const int w    = tid >> 6;
  const int lr   = lane & 15;
  const int lg   = lane >> 4;

  // per-lane base into bf16 W [n][k]: row = w*64 + lr (+ j*16), k offset lg*8
  const unsigned short* wbase = Wb + (size_t)(w * 64 + lr) * K3 + lg * 8;

  f32x4 acc[2][4];
#pragma unroll
  for (int i = 0; i < 2; ++i)
#pragma unroll
    for (int j = 0; j < 4; ++j) acc[i][j] = (f32x4){0.f, 0.f, 0.f, 0.f};

  float4 ld[8];   // [0,1]=h_start [2,3]=h_end [4,5]=t_start [6,7]=t_end

  auto load_tiles = [&](int k0) {
    ld[0] = *(const float4*)(pr0 + k0);  ld[1] = *(const float4*)(pr0 + k0 + 4);
    ld[2] = *(const float4*)(pr1 + k0);  ld[3] = *(const float4*)(pr1 + k0 + 4);
    ld[4] = *(const float4*)(pr2 + k0);  ld[5] = *(const float4*)(pr2 + k0 + 4);
    ld[6] = *(const float4*)(pr3 + k0);  ld[7] = *(const float4*)(pr3 + k0 + 4);
  };

  auto store_tiles = [&](int buf) {
    short8 hv, tv, pv;
#pragma unroll
    for (int c = 0; c < 8; ++c) {
      const int v = c >> 2, e = c & 3;
      float x0 = ((const float*)&ld[v])[e];
      float x1 = ((const float*)&ld[2 + v])[e];
      float y0 = ((const float*)&ld[4 + v])[e];
      float y1 = ((const float*)&ld[6 + v])[e];
      float h = 0.5f * (x0 + x1);
      float t = 0.5f * (y0 + y1);
      float p = h * t;                       // product in fp32, rounded once
      hv[c] = (short)f2bf(h); tv[c] = (short)f2bf(t); pv[c] = (short)f2bf(p);
    }
    const int c0 = q * 8;
    *(short8*)&sA[buf][0][arow][c0] = hv;
    *(short8*)&sA[buf][1][arow][c0] = tv;
    *(short8*)&sA[buf][2][arow][c0] = pv;
  };

  load_tiles(0);
  store_tiles(0);

  for (int kt = 0; kt < 16; ++kt) {
    __syncthreads();                       // buf[kt&1] ready for all
    const int k0  = kt * BK;
    const int buf = kt & 1;
    if (kt < 15) load_tiles(k0 + BK);      // prefetch next tile into regs

#pragma unroll
    for (int ks = 0; ks < 2; ++ks) {
      const int koff = ks * 32 + lg * 8;
      short8 ah[2], at2[2], ap[2];
#pragma unroll
      for (int i = 0; i < 2; ++i) {
        ah[i]  = *(const short8*)&sA[buf][0][i * 16 + lr][koff];
        at2[i] = *(const short8*)&sA[buf][1][i * 16 + lr][koff];
        ap[i]  = *(const short8*)&sA[buf][2][i * 16 + lr][koff];
      }
#pragma unroll
      for (int j = 0; j < 4; ++j) {
        const unsigned short* wp = wbase + (size_t)j * 16 * K3 + k0 + ks * 32;
        short8 b0 = *(const short8*)(wp);          // head block of W
        short8 b1 = *(const short8*)(wp + 1024);   // tail block
        short8 b2 = *(const short8*)(wp + 2048);   // product block
#pragma unroll
        for (int i = 0; i < 2; ++i) {
          acc[i][j] = mfma_bf16(ah[i],  b0, acc[i][j]);
          acc[i][j] = mfma_bf16(at2[i], b1, acc[i][j]);
          acc[i][j] = mfma_bf16(ap[i],  b2, acc[i][j]);
        }
      }
    }
    if (kt < 15) store_tiles(buf ^ 1);     // write next buffer (race-free: barrier-separated)
  }

  // Epilogue: C/D layout row=(lane>>4)*4+reg, col=lane&15
#pragma unroll
  for (int j = 0; j < 4; ++j) {
    const int col  = w * 64 + j * 16 + lr;
    const float bv = bias[col];
#pragma unroll
    for (int i = 0; i < 2; ++i) {
      const size_t rbase = (size_t)(m0 + i * 16 + lg * 4) * NR + col;
#pragma unroll
      for (int r = 0; r < 4; ++r)
        out[rbase + (size_t)r * NR] = acc[i][j][r] + bv;
    }
  }
}

extern "C" void kernel_launch(void* const* d_in, const int* in_sizes, int n_in,
                              void* d_out, int out_size, void* d_ws, size_t ws_size,
                              hipStream_t stream) {
  const int*   pairs = (const int*)d_in[0];
  const float* hs    = (const float*)d_in[1];
  const float* W     = (const float*)d_in[2];
  const float* bias  = (const float*)d_in[3];
  float* out = (float*)d_out;
  unsigned short* Wb = (unsigned short*)d_ws;   // 1.5 MB bf16 copy of W

  wconv_kernel<<<(NR * K3 / 4) / 256, 256, 0, stream>>>(W, Wb);
  gemm_kernel<<<(NB * NP) / BM, 256, 0, stream>>>(pairs, hs, Wb, bias, out);
}

// Round 3
// 247.317 us; speedup vs baseline: 1.2343x; 1.2343x over previous
//
#include <hip/hip_runtime.h>

#define NB 32
#define NP 512
#define NS 1024
#define NH 1024
#define NR 256
#define K3 3072

#define BM 64
#define BK 64
#define KP 72   // padded LDS pitch in shorts (144 B)

typedef short short8 __attribute__((ext_vector_type(8)));
typedef __bf16 bf16x8 __attribute__((ext_vector_type(8)));
typedef float f32x4 __attribute__((ext_vector_type(4)));

__device__ __forceinline__ unsigned short f2bf(float f) {
  unsigned u = __builtin_bit_cast(unsigned, f);
  u += 0x7fffu + ((u >> 16) & 1u);   // round-to-nearest-even
  return (unsigned short)(u >> 16);
}

__device__ __forceinline__ f32x4 mfma_bf16(short8 a, short8 b, f32x4 c) {
  return __builtin_amdgcn_mfma_f32_16x16x32_bf16(
      __builtin_bit_cast(bf16x8, a), __builtin_bit_cast(bf16x8, b), c, 0, 0, 0);
}

// W fp32 [256][3072] -> FRAGMENT-MAJOR bf16 in ws:
//   WbF[kc][n16][lane] (short8), kc = k3/32 (96), n16 = n/16 (16), lane = lr + 16*lg.
//   Element: W[n16*16 + lr][kc*32 + lg*8 + e].  A wave's MFMA B-fragment load is
//   then one CONTIGUOUS 1 KB burst (16 consecutive 64B lines) instead of 16
//   lines 6 KB apart (which alias one L2 channel set and serialize).
__global__ void wconv_kernel(const float* __restrict__ W,
                             unsigned short* __restrict__ WbF) {
  int i = blockIdx.x * blockDim.x + threadIdx.x;   // short8 id, 98304 total
  int lane = i & 63, n16 = (i >> 6) & 15, kc = i >> 10;
  int lr = lane & 15, lg = lane >> 4;
  const float* src = W + (size_t)(n16 * 16 + lr) * K3 + kc * 32 + lg * 8;
  float4 a = *(const float4*)src;
  float4 b = *(const float4*)(src + 4);
  short8 o;
  o[0] = (short)f2bf(a.x); o[1] = (short)f2bf(a.y);
  o[2] = (short)f2bf(a.z); o[3] = (short)f2bf(a.w);
  o[4] = (short)f2bf(b.x); o[5] = (short)f2bf(b.y);
  o[6] = (short)f2bf(b.z); o[7] = (short)f2bf(b.w);
  *(short8*)(WbF + (size_t)i * 8) = o;
}

// Fused gather + 3-part bf16 MFMA GEMM.
// Grid: 256 blocks (M-tiles of 64 pairs), 512 threads = 8 waves; wave w owns
// output cols [w*32, w*32+32), tile 64x32. Per K-chunk (BK=64 of H): stage
// head/tail/prod 64x64 bf16 tiles in LDS (double-buffered, reg-prefetched);
// W fragments read from L2 as contiguous 1 KB bursts (frag-major layout).
__global__ __launch_bounds__(512, 2) void gemm_kernel(
    const int* __restrict__ pairs, const float* __restrict__ hs,
    const unsigned short* __restrict__ WbF, const float* __restrict__ bias,
    float* __restrict__ out) {
  __shared__ __align__(16) unsigned short sA[2][3][BM][KP];  // 55296 B
  __shared__ int sPair[BM][4];

  const int tid   = threadIdx.x;
  const int blk   = blockIdx.x;
  const int batch = blk >> 3;          // 8 M-tiles per batch (512/64)
  const int m0    = blk * BM;          // global pair-row base

  if (tid < BM) {
    int4 pr = ((const int4*)pairs)[m0 + tid];
    sPair[tid][0] = pr.x; sPair[tid][1] = pr.y;
    sPair[tid][2] = pr.z; sPair[tid][3] = pr.w;
  }
  __syncthreads();

  // --- A staging: 8 threads per pair-row, 8 cols each (2 float4 per src row) ---
  const int arow = tid >> 3;
  const int q    = tid & 7;
  const float* hb  = hs + (size_t)batch * NS * NH;
  const float* pr0 = hb + (size_t)sPair[arow][0] * NH + q * 8;  // h_start
  const float* pr1 = hb + (size_t)sPair[arow][1] * NH + q * 8;  // h_end
  const float* pr2 = hb + (size_t)sPair[arow][2] * NH + q * 8;  // t_start
  const float* pr3 = hb + (size_t)sPair[arow][3] * NH + q * 8;  // t_end

  // --- MFMA lane mapping ---
  const int lane = tid & 63;
  const int w    = tid >> 6;           // wave id 0..7, cols w*32..w*32+32
  const int lr   = lane & 15;
  const int lg   = lane >> 4;

  // frag-major W: addr(shorts) = kc*8192 + n16*512 + lane*8; this wave: n16 = w*2 + j
  const unsigned short* wb = WbF + (size_t)(w * 2) * 512 + (size_t)lane * 8;

  f32x4 acc[4][2];
#pragma unroll
  for (int i = 0; i < 4; ++i)
#pragma unroll
    for (int j = 0; j < 2; ++j) acc[i][j] = (f32x4){0.f, 0.f, 0.f, 0.f};

  float4 ld[8];   // [0,1]=h_start [2,3]=h_end [4,5]=t_start [6,7]=t_end

  auto load_tiles = [&](int k0) {
    ld[0] = *(const float4*)(pr0 + k0);  ld[1] = *(const float4*)(pr0 + k0 + 4);
    ld[2] = *(const float4*)(pr1 + k0);  ld[3] = *(const float4*)(pr1 + k0 + 4);
    ld[4] = *(const float4*)(pr2 + k0);  ld[5] = *(const float4*)(pr2 + k0 + 4);
    ld[6] = *(const float4*)(pr3 + k0);  ld[7] = *(const float4*)(pr3 + k0 + 4);
  };

  auto store_tiles = [&](int buf) {
    short8 hv, tv, pv;
#pragma unroll
    for (int c = 0; c < 8; ++c) {
      const int v = c >> 2, e = c & 3;
      float x0 = ((const float*)&ld[v])[e];
      float x1 = ((const float*)&ld[2 + v])[e];
      float y0 = ((const float*)&ld[4 + v])[e];
      float y1 = ((const float*)&ld[6 + v])[e];
      float h = 0.5f * (x0 + x1);
      float t = 0.5f * (y0 + y1);
      float p = h * t;                       // product in fp32, rounded once
      hv[c] = (short)f2bf(h); tv[c] = (short)f2bf(t); pv[c] = (short)f2bf(p);
    }
    const int c0 = q * 8;
    *(short8*)&sA[buf][0][arow][c0] = hv;
    *(short8*)&sA[buf][1][arow][c0] = tv;
    *(short8*)&sA[buf][2][arow][c0] = pv;
  };

  load_tiles(0);
  store_tiles(0);

  for (int kt = 0; kt < 16; ++kt) {
    __syncthreads();                       // buf[kt&1] ready for all
    const int buf = kt & 1;
    if (kt < 15) load_tiles(kt * BK + BK); // prefetch next tile into regs

#pragma unroll
    for (int ks = 0; ks < 2; ++ks) {
      const int koff = ks * 32 + lg * 8;
      short8 ah[4], at4[4], ap[4];
#pragma unroll
      for (int i = 0; i < 4; ++i) {
        ah[i]  = *(const short8*)&sA[buf][0][i * 16 + lr][koff];
        at4[i] = *(const short8*)&sA[buf][1][i * 16 + lr][koff];
        ap[i]  = *(const short8*)&sA[buf][2][i * 16 + lr][koff];
      }
#pragma unroll
      for (int j = 0; j < 2; ++j) {
        // kc = part*32 + kt*2 + ks ; addr = kc*8192 + (w*2+j)*512 + lane*8
        const unsigned short* wp = wb + (size_t)(kt * 2 + ks) * 8192 + (size_t)j * 512;
        short8 b0 = *(const short8*)(wp);               // head  (part 0)
        short8 b1 = *(const short8*)(wp + 32 * 8192);   // tail  (part 1)
        short8 b2 = *(const short8*)(wp + 64 * 8192);   // prod  (part 2)
#pragma unroll
        for (int i = 0; i < 4; ++i) {
          acc[i][j] = mfma_bf16(ah[i],  b0, acc[i][j]);
          acc[i][j] = mfma_bf16(at4[i], b1, acc[i][j]);
          acc[i][j] = mfma_bf16(ap[i],  b2, acc[i][j]);
        }
      }
    }
    if (kt < 15) store_tiles(buf ^ 1);     // write next buffer (barrier-separated)
  }

  // Epilogue: C/D layout row=(lane>>4)*4+reg, col=lane&15
#pragma unroll
  for (int j = 0; j < 2; ++j) {
    const int col  = w * 32 + j * 16 + lr;
    const float bv = bias[col];
#pragma unroll
    for (int i = 0; i < 4; ++i) {
      const size_t rbase = (size_t)(m0 + i * 16 + lg * 4) * NR + col;
#pragma unroll
      for (int r = 0; r < 4; ++r)
        out[rbase + (size_t)r * NR] = acc[i][j][r] + bv;
    }
  }
}

extern "C" void kernel_launch(void* const* d_in, const int* in_sizes, int n_in,
                              void* d_out, int out_size, void* d_ws, size_t ws_size,
                              hipStream_t stream) {
  const int*   pairs = (const int*)d_in[0];
  const float* hs    = (const float*)d_in[1];
  const float* W     = (const float*)d_in[2];
  const float* bias  = (const float*)d_in[3];
  float* out = (float*)d_out;
  unsigned short* WbF = (unsigned short*)d_ws;   // 1.5 MB frag-major bf16 W

  wconv_kernel<<<(96 * 16 * 64) / 256, 256, 0, stream>>>(W, WbF);
  gemm_kernel<<<(NB * NP) / BM, 512, 0, stream>>>(pairs, hs, WbF, bias, out);
}